// Round 9
// baseline (739.750 us; speedup 1.0000x reference)
//
#include <hip/hip_runtime.h>
#include <hip/hip_bf16.h>
#include <stdint.h>

typedef __bf16 bf16_t;
typedef __bf16 bf16x4 __attribute__((ext_vector_type(4)));
typedef __bf16 bf16x8 __attribute__((ext_vector_type(8)));
typedef short s16x4 __attribute__((ext_vector_type(4)));
typedef float f32x4 __attribute__((ext_vector_type(4)));

static_assert(sizeof(bf16x8) == 16, "bf16x8 must be 16B");

#define MFMA_BF16(a, b, c) __builtin_amdgcn_mfma_f32_16x16x32_bf16((a), (b), (c), 0, 0, 0)

// 16x16x16 bf16 MFMA (instruction verified in cdna4_isa.md §10).
__device__ __forceinline__ f32x4 mfma16(bf16x4 a, bf16x4 b, f32x4 c) {
#if __has_builtin(__builtin_amdgcn_mfma_f32_16x16x16bf16_1k)
  union { bf16x4 h; s16x4 s; } ua, ub;
  ua.h = a;
  ub.h = b;
  return __builtin_amdgcn_mfma_f32_16x16x16bf16_1k(ua.s, ub.s, c, 0, 0, 0);
#else
  f32x4 d = c;
  asm volatile("v_mfma_f32_16x16x16_bf16 %0, %1, %2, %0" : "+v"(d) : "v"(a), "v"(b));
  return d;
#endif
}

typedef const __attribute__((address_space(1))) void* gas_ptr;
typedef __attribute__((address_space(3))) void* las_ptr;

__device__ __forceinline__ void gload_lds16(const void* g, void* l) {
  __builtin_amdgcn_global_load_lds((gas_ptr)g, (las_ptr)l, 16, 0, 0);
}

#define NEG_BIG (-1.0e30f)

// ---------------------------------------------------------------------------
// fp32 -> bf16 convert
// ---------------------------------------------------------------------------
__global__ __launch_bounds__(256) void cvt_kernel(const float* __restrict__ src,
                                                  bf16_t* __restrict__ dst) {
  const int i = (blockIdx.x * 256 + threadIdx.x) * 4;
  const f32x4 v = *(const f32x4*)(src + i);
  bf16x4 o;
  o[0] = (bf16_t)v[0];
  o[1] = (bf16_t)v[1];
  o[2] = (bf16_t)v[2];
  o[3] = (bf16_t)v[3];
  *(bf16x4*)(dst + i) = o;
}

// ---------------------------------------------------------------------------
// GEMM (m97 structure): D[m][n] = sum_k A[m][k] * Bw[n][k]
// MODE 0: qkv epilogue -> q / k row-major (bf16), v transposed to vT[b][d][t]
// MODE 1: final epilogue -> o_f as FP32
// ---------------------------------------------------------------------------
template <int MODE>
__global__ __launch_bounds__(256, 2) void gemm_bt_kernel(
    const bf16_t* __restrict__ A, const bf16_t* __restrict__ Bw,
    bf16_t* __restrict__ o_q, bf16_t* __restrict__ o_k, bf16_t* __restrict__ o_vT,
    float* __restrict__ o_f) {
  constexpr int K = 512;
  __shared__ bf16_t As[128 * 32];
  __shared__ bf16_t Bs[128 * 32];

  const int tid = threadIdx.x;
  const int lane = tid & 63;
  const int wid = tid >> 6;
  const int quad = lane >> 4;
  const int l15 = lane & 15;
  const int wm = wid >> 1;
  const int wn = wid & 1;

  const int mt = blockIdx.x & 127;
  const int nt = blockIdx.x >> 7;
  const int row0 = mt * 128;
  const int col0 = nt * 128;

  f32x4 acc[4][4] = {};

  for (int kt = 0; kt < K; kt += 32) {
    __syncthreads();
#pragma unroll
    for (int rnd = 0; rnd < 2; rnd++) {
      const int e = (rnd * 256 + tid) * 8;
      const int r = e >> 5;
      const int c = e & 31;
      gload_lds16(A + (size_t)(row0 + r) * K + kt + c, As + e);
      gload_lds16(Bw + (size_t)(col0 + r) * K + kt + c, Bs + e);
    }
    __syncthreads();

    bf16x8 af[4], bfr[4];
#pragma unroll
    for (int i = 0; i < 4; i++)
      af[i] = *(const bf16x8*)(As + (wm * 64 + i * 16 + l15) * 32 + quad * 8);
#pragma unroll
    for (int i = 0; i < 4; i++)
      bfr[i] = *(const bf16x8*)(Bs + (wn * 64 + i * 16 + l15) * 32 + quad * 8);
#pragma unroll
    for (int mi = 0; mi < 4; mi++)
#pragma unroll
      for (int ni = 0; ni < 4; ni++)
        acc[mi][ni] = MFMA_BF16(af[mi], bfr[ni], acc[mi][ni]);
  }

#pragma unroll
  for (int mi = 0; mi < 4; mi++) {
    const int row = row0 + wm * 64 + mi * 16 + quad * 4;
#pragma unroll
    for (int ni = 0; ni < 4; ni++) {
      const int col = col0 + wn * 64 + ni * 16 + l15;
#pragma unroll
      for (int r = 0; r < 4; r++) {
        const int rr = row + r;
        if constexpr (MODE == 0) {
          const bf16_t bv = (bf16_t)acc[mi][ni][r];
          if (col < 512) {
            o_q[(size_t)rr * 512 + col] = bv;
          } else if (col < 1024) {
            o_k[(size_t)rr * 512 + (col - 512)] = bv;
          } else {
            const int bb = rr >> 12;
            const int t = rr & 4095;
            o_vT[((size_t)bb * 512 + (col - 1024)) * 4096 + t] = bv;
          }
        } else {
          o_f[(size_t)rr * 512 + col] = acc[mi][ni][r];
        }
      }
    }
  }
}

// ---------------------------------------------------------------------------
// Flash attention v3 "S^T + dbuf":
//  - 2-wave blocks (128 thr), 32-row strips (wave owns 16 rows), full-D PV.
//    Grid = 512 (4 batches x 128 strips), heavy strips first -> 2 blocks/CU.
//  - KV tile = 16. Ks[2][16x512] + Vs[2][512x16] double-buffered = 64 KB.
//    ONE __syncthreads per tile: {issue stage j+1; compute j; sync} so the
//    barrier's vmcnt(0) drain is overlapped by compute.
//  - S^T = K.Q^T via operand-swapped 16x16x32 MFMA: C-layout gives
//    col=l15=qrow, row=quad*4+r=kv. Softmax state is per-lane (qrow=l15).
//    P (post-softmax) is then ALREADY in the A-operand layout of the
//    16x16x16 MFMA (k=quad*4+j) -> NO LDS round-trip for P at all.
//  - PV: per 16-wide d-tile, B-frag = Vs[d][kv] 8B reads; D C-layout:
//    col=l15=d, row=quad*4+rr=qrow. alpha/1-l broadcasts via __shfl.
// ---------------------------------------------------------------------------
__global__ __launch_bounds__(128, 2) void attn_kernel(
    const bf16_t* __restrict__ q, const bf16_t* __restrict__ k,
    const bf16_t* __restrict__ vT, bf16_t* __restrict__ o) {
  __shared__ bf16_t Ks[2][16 * 512];  // 2 x 16 KB (chunk-XOR swizzled)
  __shared__ bf16_t Vs[2][512 * 16];  // 2 x 16 KB ([d][kv])

  const int tid = threadIdx.x;
  const int lane = tid & 63;
  const int wid = tid >> 6;
  const int quad = lane >> 4;
  const int l15 = lane & 15;

  const int b = blockIdx.x & 3;
  const int s = 127 - (int)(blockIdx.x >> 2);  // heavy-first
  const int t0 = s * 32 + wid * 16;            // this wave's q rows

  const float scale = 0.044194173824159216f;  // 1/sqrt(512)
  const bf16_t* kbase = k + (size_t)b * 4096 * 512;
  const bf16_t* vbase = vT + (size_t)b * 512 * 4096;

  // Q B-fragments (for S^T): lane holds q[t0+l15][kk*32+quad*8 .. +7]
  bf16x8 qf[16];
  {
    const bf16_t* qp = q + ((size_t)(b * 4096 + t0 + l15)) * 512 + quad * 8;
#pragma unroll
    for (int kk = 0; kk < 16; kk++) qf[kk] = *(const bf16x8*)(qp + kk * 32);
  }

  f32x4 oacc[32] = {};  // oacc[dt][rr] = O[qrow=quad*4+rr][d=dt*16+l15]
  float mrow = NEG_BIG, lrow = 0.0f;

  const int jsteps = 2 * s + 2;  // block-uniform KV-16 tiles
  const int jcomp = 2 * s + wid; // this wave's last active tile

  // prologue: stage tile 0 into buf 0
#pragma unroll
  for (int rnd = 0; rnd < 8; rnd++) {
    const int ch = rnd * 128 + tid;
    const int kr = ch >> 6;
    const int gc = (ch & 63) ^ (kr & 7);
    gload_lds16(kbase + (size_t)kr * 512 + gc * 8, &Ks[0][ch * 8]);
  }
#pragma unroll
  for (int rnd = 0; rnd < 8; rnd++) {
    const int ch = rnd * 128 + tid;
    const int vd = ch >> 1;
    gload_lds16(vbase + (size_t)vd * 4096 + (ch & 1) * 8, &Vs[0][ch * 8]);
  }
  __syncthreads();

  const int sbase = (lane & 48) + ((lane & 48) >> 2);  // lane with l15=quad*4

  for (int j = 0; j < jsteps; j++) {
    const int buf = j & 1;
    // issue next tile's staging (async) BEFORE computing this tile
    if (j + 1 < jsteps) {
      const int nb = buf ^ 1;
      const bf16_t* kg = kbase + (size_t)(j + 1) * 16 * 512;
      const bf16_t* vg = vbase + (j + 1) * 16;
#pragma unroll
      for (int rnd = 0; rnd < 8; rnd++) {
        const int ch = rnd * 128 + tid;
        const int kr = ch >> 6;
        const int gc = (ch & 63) ^ (kr & 7);
        gload_lds16(kg + (size_t)kr * 512 + gc * 8, &Ks[nb][ch * 8]);
      }
#pragma unroll
      for (int rnd = 0; rnd < 8; rnd++) {
        const int ch = rnd * 128 + tid;
        const int vd = ch >> 1;
        gload_lds16(vg + (size_t)vd * 4096 + (ch & 1) * 8, &Vs[nb][ch * 8]);
      }
    }

    if (j <= jcomp) {
      // ---- S^T[kv16 x qrow16] = K . Q^T (swizzled Ks reads)
      f32x4 sT = {};
      const bf16_t* krow = &Ks[buf][l15 * 512];
      const int sw = l15 & 7;
#pragma unroll
      for (int kk = 0; kk < 16; kk++) {
        const bf16x8 kf = *(const bf16x8*)(krow + ((kk * 4 + quad) ^ sw) * 8);
        sT = MFMA_BF16(kf, qf[kk], sT);  // A=K, B=Q -> D=S^T
      }
      // ---- mask + inf-free online softmax (state per qrow = per l15)
      const int qr = t0 + l15;
      float vv[4];
#pragma unroll
      for (int r = 0; r < 4; r++) {
        const int kvg = j * 16 + quad * 4 + r;
        vv[r] = (kvg <= qr) ? sT[r] * scale : NEG_BIG;
      }
      float mx = fmaxf(fmaxf(vv[0], vv[1]), fmaxf(vv[2], vv[3]));
      mx = fmaxf(mx, __shfl_xor(mx, 16));
      mx = fmaxf(mx, __shfl_xor(mx, 32));
      float alpha = 1.0f;
      bf16x4 pb = {};
      if (mx > 0.5f * NEG_BIG) {
        const float mnew = fmaxf(mrow, mx);
        alpha = __expf(mrow - mnew);  // finite-finite
        float rs = 0.0f;
#pragma unroll
        for (int r = 0; r < 4; r++) {
          const float p = __expf(vv[r] - mnew);  // masked -> exp(-1e30)=0
          pb[r] = (bf16_t)p;
          rs += p;
        }
        rs += __shfl_xor(rs, 16);
        rs += __shfl_xor(rs, 32);
        lrow = lrow * alpha + rs;
        mrow = mnew;
      }
      // ---- rescale O only when some row updated its max
      if (__any(alpha < 1.0f)) {
        float al[4];
#pragma unroll
        for (int rr = 0; rr < 4; rr++) al[rr] = __shfl(alpha, sbase + rr);
#pragma unroll
        for (int dt = 0; dt < 32; dt++) {
#pragma unroll
          for (int rr = 0; rr < 4; rr++) oacc[dt][rr] *= al[rr];
        }
      }
      // ---- O += P.V : x16 MFMA, A=pb (already A-layout), B from Vs
      const bf16_t* vrow = &Vs[buf][l15 * 16 + quad * 4];
#pragma unroll
      for (int dt = 0; dt < 32; dt++) {
        const bf16x4 vf = *(const bf16x4*)(vrow + dt * 256);
        oacc[dt] = mfma16(pb, vf, oacc[dt]);
      }
    }
    __syncthreads();  // drains next tile's staging (overlapped) + buf reuse
  }

  // ---- epilogue: O / l -> bf16
  const float linv = (lrow > 0.0f) ? 1.0f / lrow : 0.0f;
  float il[4];
#pragma unroll
  for (int rr = 0; rr < 4; rr++) il[rr] = __shfl(linv, sbase + rr);
#pragma unroll
  for (int rr = 0; rr < 4; rr++) {
    bf16_t* orow = o + ((size_t)(b * 4096 + t0 + quad * 4 + rr)) * 512 + l15;
#pragma unroll
    for (int dt = 0; dt < 32; dt++) orow[dt * 16] = (bf16_t)(oacc[dt][rr] * il[rr]);
  }
}

// ---------------------------------------------------------------------------
extern "C" void kernel_launch(void* const* d_in, const int* in_sizes, int n_in,
                              void* d_out, int out_size, void* d_ws, size_t ws_size,
                              hipStream_t stream) {
  const float* x_f = (const float*)d_in[0];   // [4,4096,512] fp32
  const float* wq_f = (const float*)d_in[1];  // [1536,512]   fp32
  const float* wp_f = (const float*)d_in[2];  // [512,512]    fp32
  float* out = (float*)d_out;                 // [4,4096,512] fp32

  // ws (bf16): xb (16MB, reused as attn output) | wqb | wpb | q | k | vT
  bf16_t* xb = (bf16_t*)d_ws;
  bf16_t* wqb = xb + (size_t)16384 * 512;
  bf16_t* wpb = wqb + (size_t)1536 * 512;
  bf16_t* q = wpb + (size_t)512 * 512;
  bf16_t* kk = q + (size_t)16384 * 512;
  bf16_t* vT = kk + (size_t)16384 * 512;

  // 0) convert fp32 inputs -> bf16
  cvt_kernel<<<(16384 * 512) / 1024, 256, 0, stream>>>(x_f, xb);
  cvt_kernel<<<(1536 * 512) / 1024, 256, 0, stream>>>(wq_f, wqb);
  cvt_kernel<<<(512 * 512) / 1024, 256, 0, stream>>>(wp_f, wpb);

  // 1) qkv = x @ Wqkv^T ; v stored transposed (xb dead afterwards)
  gemm_bt_kernel<0><<<128 * 12, 256, 0, stream>>>(xb, wqb, q, kk, vT, nullptr);
  // 2) causal attention -> xb (512 blocks x 128 thr, dbuf K-loop)
  attn_kernel<<<512, 128, 0, stream>>>(q, kk, vT, xb);
  // 3) y = attn @ Wproj^T -> fp32 d_out
  gemm_bt_kernel<1><<<128 * 4, 256, 0, stream>>>(xb, wpb, nullptr, nullptr, nullptr, out);
}